// Round 13
// baseline (605.763 us; speedup 1.0000x reference)
//
#include <hip/hip_runtime.h>

// GCN regressor, round 12 (resubmit after infra failure):
//  - agg16: XCD-aware channel split. Blocks on XCDs 0-3 gather channels 0-31,
//    XCDs 4-7 gather 32-63 (blockIdx%8 ~ XCD). Halves each XCD's L2 working
//    set (25.6 -> 12.8 MB) to raise hit rate on the random row gather.
//    Wave = 2 nodes x 32 lanes (128 B coalesced per half-row).
//  - CSR build: fixed-capacity bins, packed u32 staged, place2.
//  - GEMMs on mfma_f32_16x16x32_bf16 (W->bf16^T in LDS, dinv-scaled bf16 out).

constexpr int HID = 128;
constexpr int BIN_SHIFT = 8;          // 256 dst nodes per bin
constexpr int MAXBINS = 512;          // nN <= 131072
constexpr int CAP_SHIFT = 14;         // 16384 staged slots per bin (~2x mean)

typedef float f32x4 __attribute__((ext_vector_type(4)));
typedef short short8 __attribute__((ext_vector_type(8)));

static __device__ __forceinline__ unsigned bf16rne(float f) {
    unsigned u = __float_as_uint(f);
    return (u + 0x7FFFu + ((u >> 16) & 1u)) >> 16;
}
static __device__ __forceinline__ unsigned packbf16(float lo, float hi) {
    return bf16rne(lo) | (bf16rne(hi) << 16);
}
static __device__ __forceinline__ float blo(unsigned u) { return __uint_as_float(u << 16); }
static __device__ __forceinline__ float bhi(unsigned u) { return __uint_as_float(u & 0xFFFF0000u); }

// ---------------- CSR build (fixed-capacity bins) ----------------
__global__ __launch_bounds__(256) void k_initcur(int* __restrict__ bin_cur, int nbins) {
    int b = blockIdx.x * 256 + threadIdx.x;
    if (b < nbins) bin_cur[b] = b << CAP_SHIFT;
}

__global__ __launch_bounds__(256) void k_stage(const int* __restrict__ src,
                                               const int* __restrict__ dst,
                                               int* __restrict__ bin_cursor,
                                               unsigned* __restrict__ staged,
                                               int nE, int nbins) {
    __shared__ int hist[MAXBINS];
    __shared__ int wbase[MAXBINS];
    __shared__ int rank[MAXBINS];
    const int tid = threadIdx.x;
    const long long e0 = (long long)blockIdx.x * 4096;
    int es[16], ed[16];
#pragma unroll
    for (int k = 0; k < 16; ++k) {
        long long e = e0 + k * 256 + tid;
        if (e < nE) { es[k] = src[e]; ed[k] = dst[e]; }
        else        { es[k] = 0; ed[k] = -1; }
    }
    for (int t = tid; t < nbins; t += 256) { hist[t] = 0; rank[t] = 0; }
    __syncthreads();
#pragma unroll
    for (int k = 0; k < 16; ++k)
        if (ed[k] >= 0) atomicAdd(&hist[ed[k] >> BIN_SHIFT], 1);
    __syncthreads();
    for (int t = tid; t < nbins; t += 256)
        wbase[t] = hist[t] ? atomicAdd(&bin_cursor[t], hist[t]) : 0;
    __syncthreads();
#pragma unroll
    for (int k = 0; k < 16; ++k)
        if (ed[k] >= 0) {
            int b = ed[k] >> BIN_SHIFT;
            int r = atomicAdd(&rank[b], 1);
            int w = wbase[b] + r;
            if (w < ((b + 1) << CAP_SHIFT))   // overflow guard
                staged[w] = ((unsigned)(ed[k] & ((1 << BIN_SHIFT) - 1)) << 24) | (unsigned)es[k];
        }
}

__global__ __launch_bounds__(256) void k_place2(const int* __restrict__ bin_cur,
                                                const unsigned* __restrict__ staged,
                                                int* __restrict__ esrc,
                                                int* __restrict__ row_start,
                                                int* __restrict__ row_end,
                                                float* __restrict__ dinv, int nN) {
    __shared__ int cnt[1 << BIN_SHIFT];
    __shared__ int sc[1 << BIN_SHIFT];
    const int b = blockIdx.x;
    const int tid = threadIdx.x;
    const int d0 = b << BIN_SHIFT;
    const int dend = min(d0 + (1 << BIN_SHIFT), nN);
    const int p0 = b << CAP_SHIFT;
    const int p1 = bin_cur[b];
    cnt[tid] = 0;
    __syncthreads();
    for (int i = p0 + tid; i < p1; i += 256)
        atomicAdd(&cnt[staged[i] >> 24], 1);
    __syncthreads();
    const int my = cnt[tid];
    sc[tid] = my;
    __syncthreads();
    for (int off = 1; off < 256; off <<= 1) {
        int v = (tid >= off) ? sc[tid - off] : 0;
        __syncthreads();
        sc[tid] += v;
        __syncthreads();
    }
    const int excl = sc[tid] - my;
    const int d = d0 + tid;
    if (d < dend) {
        row_start[d] = p0 + excl;
        row_end[d]   = p0 + excl + my;
        dinv[d] = rsqrtf((float)my + 1.0f);   // +1 self-loop
    }
    __syncthreads();
    cnt[tid] = p0 + excl;   // reuse as cursor
    __syncthreads();
    for (int i = p0 + tid; i < p1; i += 256) {
        unsigned pr = staged[i];
        int pos = atomicAdd(&cnt[pr >> 24], 1);
        esrc[pos] = (int)(pr & 0xFFFFFFu);
    }
}

// ---------------- MFMA GEMM: h16[r] = bf16( (A[r,:]@W) * dinv[r] ) --------
template <bool A_F32>
__global__ __launch_bounds__(256) void k_gemm_mfma(const void* __restrict__ Aptr,
                                                   const float* __restrict__ W,
                                                   const float* __restrict__ dinv,
                                                   unsigned* __restrict__ h16, int n) {
    __shared__ unsigned lds[128 * 68];   // Wt bf16 [col][k2] stride 68; reused as C-bounce
    const int tid  = threadIdx.x;
    const int lane = tid & 63;
    const int w    = tid >> 6;
    const int colb = lane & 15;
    const int kg   = lane >> 4;
    const int row0 = blockIdx.x * 64;

    for (int it = 0; it < 32; ++it) {
        int f = it * 256 + tid;
        int c = f & 127, k2 = f >> 7;
        float w0 = W[(size_t)(2 * k2) * HID + c];
        float w1 = W[(size_t)(2 * k2 + 1) * HID + c];
        lds[c * 68 + k2] = packbf16(w0, w1);
    }

    const int r = row0 + w * 16 + colb;
    uint4 a[4] = {};
    if (r < n) {
        if constexpr (A_F32) {
            const float* A = (const float*)Aptr;
#pragma unroll
            for (int kc = 0; kc < 4; ++kc) {
                const float* p = A + (size_t)r * HID + kc * 32 + kg * 8;
                float4 f0 = *(const float4*)(p);
                float4 f1 = *(const float4*)(p + 4);
                a[kc].x = packbf16(f0.x, f0.y);
                a[kc].y = packbf16(f0.z, f0.w);
                a[kc].z = packbf16(f1.x, f1.y);
                a[kc].w = packbf16(f1.z, f1.w);
            }
        } else {
            const unsigned* A16 = (const unsigned*)Aptr;
#pragma unroll
            for (int kc = 0; kc < 4; ++kc)
                a[kc] = *(const uint4*)(A16 + (size_t)r * 64 + kc * 16 + kg * 4);
        }
    }
    __syncthreads();

    f32x4 acc[8] = {};
#pragma unroll
    for (int ct = 0; ct < 8; ++ct) {
#pragma unroll
        for (int kc = 0; kc < 4; ++kc) {
            uint4 bu = *(const uint4*)&lds[(ct * 16 + colb) * 68 + kc * 16 + kg * 4];
            acc[ct] = __builtin_amdgcn_mfma_f32_16x16x32_bf16(
                __builtin_bit_cast(short8, a[kc]),
                __builtin_bit_cast(short8, bu),
                acc[ct], 0, 0, 0);
        }
    }

    __syncthreads();
    float* Cb = (float*)lds;             // [64][132]
#pragma unroll
    for (int ct = 0; ct < 8; ++ct)
#pragma unroll
        for (int reg = 0; reg < 4; ++reg)
            Cb[(w * 16 + kg * 4 + reg) * 132 + ct * 16 + colb] = acc[ct][reg];
    __syncthreads();
    for (int it = 0; it < 16; ++it) {
        int f = it * 256 + tid;
        int rl = f >> 6, cw = f & 63;
        int gr = row0 + rl;
        if (gr < n) {
            float di = dinv[gr];
            float2 v = *(const float2*)&Cb[rl * 132 + 2 * cw];
            h16[(size_t)gr * 64 + cw] = packbf16(v.x * di, v.y * di);
        }
    }
}

// ---------------- gather-aggregate, XCD channel-split ---------------------
// Wave = 2 nodes x 32 lanes; block handles 8 nodes for ONE channel half.
// Mapping: xcd = bid&7; half = xcd>>2; group g covers nodes [g*8, g*8+8).
__global__ __launch_bounds__(256) void k_agg16h(const int* __restrict__ row_start,
                                                const int* __restrict__ row_end,
                                                const int* __restrict__ esrc,
                                                const float* __restrict__ dinv,
                                                const unsigned* __restrict__ h16,
                                                const float* __restrict__ bias,
                                                unsigned* __restrict__ out16, int n,
                                                float* __restrict__ pool_sums,
                                                const int* __restrict__ batch) {
    const int bid  = blockIdx.x;
    const int xcd  = bid & 7;
    const int half = xcd >> 2;                      // 0: ch 0-31, 1: ch 32-63
    const int g    = ((bid >> 3) << 2) + (xcd & 3); // node group
    const int w    = threadIdx.x >> 6;
    const int lane = threadIdx.x & 63;
    const int node = g * 8 + w * 2 + (lane >> 5);
    if (node >= n) return;
    const int ch = (lane & 31) + half * 32;

    int e0 = row_start[node], e1 = row_end[node];
    float dd = dinv[node];

    unsigned su = h16[(size_t)node * 64 + ch];      // self row (pre-scaled)
    float ax = blo(su), ay = bhi(su);

    int e = e0;
    for (; e + 4 <= e1; e += 4) {
        int s0 = esrc[e + 0], s1 = esrc[e + 1], s2 = esrc[e + 2], s3 = esrc[e + 3];
        unsigned u0 = h16[(size_t)s0 * 64 + ch];
        unsigned u1 = h16[(size_t)s1 * 64 + ch];
        unsigned u2 = h16[(size_t)s2 * 64 + ch];
        unsigned u3 = h16[(size_t)s3 * 64 + ch];
        ax += blo(u0) + blo(u1) + blo(u2) + blo(u3);
        ay += bhi(u0) + bhi(u1) + bhi(u2) + bhi(u3);
    }
    for (; e < e1; ++e) {
        int s = esrc[e];
        unsigned u = h16[(size_t)s * 64 + ch];
        ax += blo(u);
        ay += bhi(u);
    }

    const float2 bv = *(const float2*)(bias + 2 * ch);
    float ox = fmaxf(ax * dd + bv.x, 0.f);
    float oy = fmaxf(ay * dd + bv.y, 0.f);
    if (out16) {
        out16[(size_t)node * 64 + ch] = packbf16(ox, oy);
    } else {
        float* p = &pool_sums[(size_t)batch[node] * HID + 2 * ch];
        atomicAdd(p, ox);
        atomicAdd(p + 1, oy);
    }
}

// ---------------- pooling / head ----------------
__global__ __launch_bounds__(256) void k_count(const int* __restrict__ batch,
                                               float* __restrict__ cnt, int n) {
    int i = blockIdx.x * 256 + threadIdx.x;
    if (i < n) atomicAdd(&cnt[batch[i]], 1.0f);
}

__global__ __launch_bounds__(64) void k_mlp(const float* __restrict__ sums,
                                            const float* __restrict__ cnt,
                                            const float* __restrict__ lw1,
                                            const float* __restrict__ lb1,
                                            const float* __restrict__ lw2,
                                            const float* __restrict__ lb2,
                                            float* __restrict__ out) {
    int g = blockIdx.x;
    int j = threadIdx.x;
    float inv = 1.0f / fmaxf(cnt[g], 1.0f);
    const float* srow = sums + (size_t)g * HID;
    float acc = lb1[j];
#pragma unroll 8
    for (int k = 0; k < HID; ++k) acc += srow[k] * inv * lw1[k * 64 + j];
    acc = fmaxf(acc, 0.0f);
    float prod = acc * lw2[j];
#pragma unroll
    for (int off = 32; off > 0; off >>= 1) prod += __shfl_down(prod, off);
    if (j == 0) out[g] = prod + lb2[0];
}

extern "C" void kernel_launch(void* const* d_in, const int* in_sizes, int n_in,
                              void* d_out, int out_size, void* d_ws, size_t ws_size,
                              hipStream_t stream) {
    const float* x   = (const float*)d_in[0];
    const int*   ei  = (const int*)d_in[1];
    const int*   bat = (const int*)d_in[2];
    const float* W1  = (const float*)d_in[3];
    const float* b1  = (const float*)d_in[4];
    const float* W2  = (const float*)d_in[5];
    const float* b2  = (const float*)d_in[6];
    const float* W3  = (const float*)d_in[7];
    const float* b3  = (const float*)d_in[8];
    const float* lw1 = (const float*)d_in[9];
    const float* lb1 = (const float*)d_in[10];
    const float* lw2 = (const float*)d_in[11];
    const float* lb2 = (const float*)d_in[12];
    float* out = (float*)d_out;

    const int nN = in_sizes[2];       // 100000
    const int nE = in_sizes[1] / 2;   // 3200000
    const int G  = out_size;          // 4096
    const int* src = ei;
    const int* dst = ei + nE;

    const int nbins = (nN + (1 << BIN_SHIFT) - 1) >> BIN_SHIFT;  // 391 (<=512)
    const size_t capTotal = (size_t)nbins << CAP_SHIFT;

    // workspace layout
    char* p = (char*)d_ws;
    auto alloc = [&](size_t bytes) { char* r = p; p += (bytes + 255) & ~(size_t)255; return r; };
    unsigned* act16     = (unsigned*)alloc(sizeof(unsigned) * (size_t)nN * 64);
    unsigned* h16       = (unsigned*)alloc(sizeof(unsigned) * ((size_t)nN * 64 > capTotal ? (size_t)nN * 64 : capTotal));
    float*    dinv      = (float*)alloc(sizeof(float) * nN);
    float*    sums      = (float*)alloc(sizeof(float) * (size_t)G * HID);
    float*    cnt       = (float*)alloc(sizeof(float) * G);
    int*      bin_cur   = (int*)alloc(sizeof(int) * (nbins + 1));
    int*      row_start = (int*)alloc(sizeof(int) * nN);
    int*      row_end   = (int*)alloc(sizeof(int) * nN);
    int*      esrc      = (int*)alloc(sizeof(int) * capTotal);
    unsigned* staged    = (unsigned*)h16;  // consumed by k_place2 before gemm writes h16

    const int gemmGrid = (nN + 63) / 64;
    const int edgeWGs  = (int)(((long long)nE + 4095) / 4096);
    // agg grid: 8 nodes/block, groups padded to x4, x2 halves
    const int ngroups  = (((nN + 7) / 8 + 3) / 4) * 4;
    const int aggGrid  = ngroups * 2;

    // ---- CSR build (fixed-capacity bins) ----
    k_initcur<<<(nbins + 255) / 256, 256, 0, stream>>>(bin_cur, nbins);
    k_stage<<<edgeWGs, 256, 0, stream>>>(src, dst, bin_cur, staged, nE, nbins);
    k_place2<<<nbins, 256, 0, stream>>>(bin_cur, staged, esrc, row_start, row_end, dinv, nN);

    // ---- pooling denominators ----
    hipMemsetAsync(sums, 0, sizeof(float) * ((size_t)G * HID + G), stream);
    k_count<<<(nN + 255) / 256, 256, 0, stream>>>(bat, cnt, nN);

    // ---- 3 GCN layers (MFMA GEMM + XCD-split gather-agg) ----
    k_gemm_mfma<true ><<<gemmGrid, 256, 0, stream>>>(x, W1, dinv, h16, nN);
    k_agg16h<<<aggGrid, 256, 0, stream>>>(row_start, row_end, esrc, dinv, h16, b1, act16, nN, nullptr, nullptr);
    k_gemm_mfma<false><<<gemmGrid, 256, 0, stream>>>(act16, W2, dinv, h16, nN);
    k_agg16h<<<aggGrid, 256, 0, stream>>>(row_start, row_end, esrc, dinv, h16, b2, act16, nN, nullptr, nullptr);
    k_gemm_mfma<false><<<gemmGrid, 256, 0, stream>>>(act16, W3, dinv, h16, nN);
    k_agg16h<<<aggGrid, 256, 0, stream>>>(row_start, row_end, esrc, dinv, h16, b3, nullptr, nN, sums, bat);

    // ---- head ----
    k_mlp<<<G, 64, 0, stream>>>(sums, cnt, lw1, lb1, lw2, lb2, out);
}

// Round 14
// 513.256 us; speedup vs baseline: 1.1802x; 1.1802x over previous
//
#include <hip/hip_runtime.h>

// GCN regressor, round 14 (revert R13's channel split; R11 structure + nt esrc):
//  - agg16: wave-per-node, wave-uniform edge loop (readfirstlane scalar path),
//    bf16 rows pre-scaled by dinv[src]; esrc via nontemporal loads (stream-once,
//    keep L2 for the h16 gather working set).
//  - CSR build: fixed-capacity bins, packed u32 staged, place2.
//  - GEMMs on mfma_f32_16x16x32_bf16 (W->bf16^T in LDS, dinv-scaled bf16 out).

constexpr int HID = 128;
constexpr int BIN_SHIFT = 8;          // 256 dst nodes per bin
constexpr int MAXBINS = 512;          // nN <= 131072
constexpr int CAP_SHIFT = 14;         // 16384 staged slots per bin (~2x mean)

typedef float f32x4 __attribute__((ext_vector_type(4)));
typedef short short8 __attribute__((ext_vector_type(8)));

static __device__ __forceinline__ unsigned bf16rne(float f) {
    unsigned u = __float_as_uint(f);
    return (u + 0x7FFFu + ((u >> 16) & 1u)) >> 16;
}
static __device__ __forceinline__ unsigned packbf16(float lo, float hi) {
    return bf16rne(lo) | (bf16rne(hi) << 16);
}
static __device__ __forceinline__ float blo(unsigned u) { return __uint_as_float(u << 16); }
static __device__ __forceinline__ float bhi(unsigned u) { return __uint_as_float(u & 0xFFFF0000u); }

// ---------------- CSR build (fixed-capacity bins) ----------------
__global__ __launch_bounds__(256) void k_initcur(int* __restrict__ bin_cur, int nbins) {
    int b = blockIdx.x * 256 + threadIdx.x;
    if (b < nbins) bin_cur[b] = b << CAP_SHIFT;
}

__global__ __launch_bounds__(256) void k_stage(const int* __restrict__ src,
                                               const int* __restrict__ dst,
                                               int* __restrict__ bin_cursor,
                                               unsigned* __restrict__ staged,
                                               int nE, int nbins) {
    __shared__ int hist[MAXBINS];
    __shared__ int wbase[MAXBINS];
    __shared__ int rank[MAXBINS];
    const int tid = threadIdx.x;
    const long long e0 = (long long)blockIdx.x * 4096;
    int es[16], ed[16];
#pragma unroll
    for (int k = 0; k < 16; ++k) {
        long long e = e0 + k * 256 + tid;
        if (e < nE) { es[k] = src[e]; ed[k] = dst[e]; }
        else        { es[k] = 0; ed[k] = -1; }
    }
    for (int t = tid; t < nbins; t += 256) { hist[t] = 0; rank[t] = 0; }
    __syncthreads();
#pragma unroll
    for (int k = 0; k < 16; ++k)
        if (ed[k] >= 0) atomicAdd(&hist[ed[k] >> BIN_SHIFT], 1);
    __syncthreads();
    for (int t = tid; t < nbins; t += 256)
        wbase[t] = hist[t] ? atomicAdd(&bin_cursor[t], hist[t]) : 0;
    __syncthreads();
#pragma unroll
    for (int k = 0; k < 16; ++k)
        if (ed[k] >= 0) {
            int b = ed[k] >> BIN_SHIFT;
            int r = atomicAdd(&rank[b], 1);
            int w = wbase[b] + r;
            if (w < ((b + 1) << CAP_SHIFT))   // overflow guard
                staged[w] = ((unsigned)(ed[k] & ((1 << BIN_SHIFT) - 1)) << 24) | (unsigned)es[k];
        }
}

__global__ __launch_bounds__(256) void k_place2(const int* __restrict__ bin_cur,
                                                const unsigned* __restrict__ staged,
                                                int* __restrict__ esrc,
                                                int* __restrict__ row_start,
                                                int* __restrict__ row_end,
                                                float* __restrict__ dinv, int nN) {
    __shared__ int cnt[1 << BIN_SHIFT];
    __shared__ int sc[1 << BIN_SHIFT];
    const int b = blockIdx.x;
    const int tid = threadIdx.x;
    const int d0 = b << BIN_SHIFT;
    const int dend = min(d0 + (1 << BIN_SHIFT), nN);
    const int p0 = b << CAP_SHIFT;
    const int p1 = bin_cur[b];
    cnt[tid] = 0;
    __syncthreads();
    for (int i = p0 + tid; i < p1; i += 256)
        atomicAdd(&cnt[staged[i] >> 24], 1);
    __syncthreads();
    const int my = cnt[tid];
    sc[tid] = my;
    __syncthreads();
    for (int off = 1; off < 256; off <<= 1) {
        int v = (tid >= off) ? sc[tid - off] : 0;
        __syncthreads();
        sc[tid] += v;
        __syncthreads();
    }
    const int excl = sc[tid] - my;
    const int d = d0 + tid;
    if (d < dend) {
        row_start[d] = p0 + excl;
        row_end[d]   = p0 + excl + my;
        dinv[d] = rsqrtf((float)my + 1.0f);   // +1 self-loop
    }
    __syncthreads();
    cnt[tid] = p0 + excl;   // reuse as cursor
    __syncthreads();
    for (int i = p0 + tid; i < p1; i += 256) {
        unsigned pr = staged[i];
        int pos = atomicAdd(&cnt[pr >> 24], 1);
        esrc[pos] = (int)(pr & 0xFFFFFFu);
    }
}

// ---------------- MFMA GEMM: h16[r] = bf16( (A[r,:]@W) * dinv[r] ) --------
template <bool A_F32>
__global__ __launch_bounds__(256) void k_gemm_mfma(const void* __restrict__ Aptr,
                                                   const float* __restrict__ W,
                                                   const float* __restrict__ dinv,
                                                   unsigned* __restrict__ h16, int n) {
    __shared__ unsigned lds[128 * 68];   // Wt bf16 [col][k2] stride 68; reused as C-bounce
    const int tid  = threadIdx.x;
    const int lane = tid & 63;
    const int w    = tid >> 6;
    const int colb = lane & 15;
    const int kg   = lane >> 4;
    const int row0 = blockIdx.x * 64;

    for (int it = 0; it < 32; ++it) {
        int f = it * 256 + tid;
        int c = f & 127, k2 = f >> 7;
        float w0 = W[(size_t)(2 * k2) * HID + c];
        float w1 = W[(size_t)(2 * k2 + 1) * HID + c];
        lds[c * 68 + k2] = packbf16(w0, w1);
    }

    const int r = row0 + w * 16 + colb;
    uint4 a[4] = {};
    if (r < n) {
        if constexpr (A_F32) {
            const float* A = (const float*)Aptr;
#pragma unroll
            for (int kc = 0; kc < 4; ++kc) {
                const float* p = A + (size_t)r * HID + kc * 32 + kg * 8;
                float4 f0 = *(const float4*)(p);
                float4 f1 = *(const float4*)(p + 4);
                a[kc].x = packbf16(f0.x, f0.y);
                a[kc].y = packbf16(f0.z, f0.w);
                a[kc].z = packbf16(f1.x, f1.y);
                a[kc].w = packbf16(f1.z, f1.w);
            }
        } else {
            const unsigned* A16 = (const unsigned*)Aptr;
#pragma unroll
            for (int kc = 0; kc < 4; ++kc)
                a[kc] = *(const uint4*)(A16 + (size_t)r * 64 + kc * 16 + kg * 4);
        }
    }
    __syncthreads();

    f32x4 acc[8] = {};
#pragma unroll
    for (int ct = 0; ct < 8; ++ct) {
#pragma unroll
        for (int kc = 0; kc < 4; ++kc) {
            uint4 bu = *(const uint4*)&lds[(ct * 16 + colb) * 68 + kc * 16 + kg * 4];
            acc[ct] = __builtin_amdgcn_mfma_f32_16x16x32_bf16(
                __builtin_bit_cast(short8, a[kc]),
                __builtin_bit_cast(short8, bu),
                acc[ct], 0, 0, 0);
        }
    }

    __syncthreads();
    float* Cb = (float*)lds;             // [64][132]
#pragma unroll
    for (int ct = 0; ct < 8; ++ct)
#pragma unroll
        for (int reg = 0; reg < 4; ++reg)
            Cb[(w * 16 + kg * 4 + reg) * 132 + ct * 16 + colb] = acc[ct][reg];
    __syncthreads();
    for (int it = 0; it < 16; ++it) {
        int f = it * 256 + tid;
        int rl = f >> 6, cw = f & 63;
        int gr = row0 + rl;
        if (gr < n) {
            float di = dinv[gr];
            float2 v = *(const float2*)&Cb[rl * 132 + 2 * cw];
            h16[(size_t)gr * 64 + cw] = packbf16(v.x * di, v.y * di);
        }
    }
}

// ---------------- fused gather-aggregate + bias + ReLU --------------------
// One wave per dst node; lane owns 2 channels (one u32 = 2 bf16). Rows are
// pre-scaled by dinv[src]; out = relu(dd * (sum_nbr + self) + b).
// esrc is stream-once -> nontemporal loads (don't pollute L2's h16 set).
__global__ __launch_bounds__(256) void k_agg16(const int* __restrict__ row_start,
                                               const int* __restrict__ row_end,
                                               const int* __restrict__ esrc,
                                               const float* __restrict__ dinv,
                                               const unsigned* __restrict__ h16,
                                               const float* __restrict__ bias,
                                               unsigned* __restrict__ out16, int n,
                                               float* __restrict__ pool_sums,
                                               const int* __restrict__ batch) {
    int t = blockIdx.x * 256 + threadIdx.x;
    int node = t >> 6;
    if (node >= n) return;
    const int lane = t & 63;
    int e0 = row_start[node], e1 = row_end[node];
    e0 = __builtin_amdgcn_readfirstlane(e0);
    e1 = __builtin_amdgcn_readfirstlane(e1);
    float dd = dinv[node];

    unsigned su = h16[(size_t)node * 64 + lane];   // self row (pre-scaled)
    float ax = blo(su), ay = bhi(su);

    int e = e0;
    for (; e + 4 <= e1; e += 4) {
        int s0 = __builtin_amdgcn_readfirstlane(__builtin_nontemporal_load(esrc + e + 0));
        int s1 = __builtin_amdgcn_readfirstlane(__builtin_nontemporal_load(esrc + e + 1));
        int s2 = __builtin_amdgcn_readfirstlane(__builtin_nontemporal_load(esrc + e + 2));
        int s3 = __builtin_amdgcn_readfirstlane(__builtin_nontemporal_load(esrc + e + 3));
        unsigned u0 = h16[(size_t)s0 * 64 + lane];
        unsigned u1 = h16[(size_t)s1 * 64 + lane];
        unsigned u2 = h16[(size_t)s2 * 64 + lane];
        unsigned u3 = h16[(size_t)s3 * 64 + lane];
        ax += blo(u0) + blo(u1) + blo(u2) + blo(u3);
        ay += bhi(u0) + bhi(u1) + bhi(u2) + bhi(u3);
    }
    for (; e < e1; ++e) {
        int s = __builtin_amdgcn_readfirstlane(__builtin_nontemporal_load(esrc + e));
        unsigned u = h16[(size_t)s * 64 + lane];
        ax += blo(u);
        ay += bhi(u);
    }

    const float2 bv = *(const float2*)(bias + 2 * lane);
    float ox = fmaxf(ax * dd + bv.x, 0.f);
    float oy = fmaxf(ay * dd + bv.y, 0.f);
    if (out16) {
        out16[(size_t)node * 64 + lane] = packbf16(ox, oy);
    } else {
        float* p = &pool_sums[(size_t)batch[node] * HID + 2 * lane];
        atomicAdd(p, ox);
        atomicAdd(p + 1, oy);
    }
}

// ---------------- pooling / head ----------------
__global__ __launch_bounds__(256) void k_count(const int* __restrict__ batch,
                                               float* __restrict__ cnt, int n) {
    int i = blockIdx.x * 256 + threadIdx.x;
    if (i < n) atomicAdd(&cnt[batch[i]], 1.0f);
}

__global__ __launch_bounds__(64) void k_mlp(const float* __restrict__ sums,
                                            const float* __restrict__ cnt,
                                            const float* __restrict__ lw1,
                                            const float* __restrict__ lb1,
                                            const float* __restrict__ lw2,
                                            const float* __restrict__ lb2,
                                            float* __restrict__ out) {
    int g = blockIdx.x;
    int j = threadIdx.x;
    float inv = 1.0f / fmaxf(cnt[g], 1.0f);
    const float* srow = sums + (size_t)g * HID;
    float acc = lb1[j];
#pragma unroll 8
    for (int k = 0; k < HID; ++k) acc += srow[k] * inv * lw1[k * 64 + j];
    acc = fmaxf(acc, 0.0f);
    float prod = acc * lw2[j];
#pragma unroll
    for (int off = 32; off > 0; off >>= 1) prod += __shfl_down(prod, off);
    if (j == 0) out[g] = prod + lb2[0];
}

extern "C" void kernel_launch(void* const* d_in, const int* in_sizes, int n_in,
                              void* d_out, int out_size, void* d_ws, size_t ws_size,
                              hipStream_t stream) {
    const float* x   = (const float*)d_in[0];
    const int*   ei  = (const int*)d_in[1];
    const int*   bat = (const int*)d_in[2];
    const float* W1  = (const float*)d_in[3];
    const float* b1  = (const float*)d_in[4];
    const float* W2  = (const float*)d_in[5];
    const float* b2  = (const float*)d_in[6];
    const float* W3  = (const float*)d_in[7];
    const float* b3  = (const float*)d_in[8];
    const float* lw1 = (const float*)d_in[9];
    const float* lb1 = (const float*)d_in[10];
    const float* lw2 = (const float*)d_in[11];
    const float* lb2 = (const float*)d_in[12];
    float* out = (float*)d_out;

    const int nN = in_sizes[2];       // 100000
    const int nE = in_sizes[1] / 2;   // 3200000
    const int G  = out_size;          // 4096
    const int* src = ei;
    const int* dst = ei + nE;

    const int nbins = (nN + (1 << BIN_SHIFT) - 1) >> BIN_SHIFT;  // 391 (<=512)
    const size_t capTotal = (size_t)nbins << CAP_SHIFT;

    // workspace layout
    char* p = (char*)d_ws;
    auto alloc = [&](size_t bytes) { char* r = p; p += (bytes + 255) & ~(size_t)255; return r; };
    unsigned* act16     = (unsigned*)alloc(sizeof(unsigned) * (size_t)nN * 64);
    unsigned* h16       = (unsigned*)alloc(sizeof(unsigned) * ((size_t)nN * 64 > capTotal ? (size_t)nN * 64 : capTotal));
    float*    dinv      = (float*)alloc(sizeof(float) * nN);
    float*    sums      = (float*)alloc(sizeof(float) * (size_t)G * HID);
    float*    cnt       = (float*)alloc(sizeof(float) * G);
    int*      bin_cur   = (int*)alloc(sizeof(int) * (nbins + 1));
    int*      row_start = (int*)alloc(sizeof(int) * nN);
    int*      row_end   = (int*)alloc(sizeof(int) * nN);
    int*      esrc      = (int*)alloc(sizeof(int) * capTotal);
    unsigned* staged    = (unsigned*)h16;  // consumed by k_place2 before gemm writes h16

    const int gemmGrid = (nN + 63) / 64;
    const int aggGrid  = (int)(((long long)nN * 64 + 255) / 256);
    const int edgeWGs  = (int)(((long long)nE + 4095) / 4096);

    // ---- CSR build (fixed-capacity bins) ----
    k_initcur<<<(nbins + 255) / 256, 256, 0, stream>>>(bin_cur, nbins);
    k_stage<<<edgeWGs, 256, 0, stream>>>(src, dst, bin_cur, staged, nE, nbins);
    k_place2<<<nbins, 256, 0, stream>>>(bin_cur, staged, esrc, row_start, row_end, dinv, nN);

    // ---- pooling denominators ----
    hipMemsetAsync(sums, 0, sizeof(float) * ((size_t)G * HID + G), stream);
    k_count<<<(nN + 255) / 256, 256, 0, stream>>>(bat, cnt, nN);

    // ---- 3 GCN layers (MFMA GEMM + gather-agg) ----
    k_gemm_mfma<true ><<<gemmGrid, 256, 0, stream>>>(x, W1, dinv, h16, nN);
    k_agg16<<<aggGrid, 256, 0, stream>>>(row_start, row_end, esrc, dinv, h16, b1, act16, nN, nullptr, nullptr);
    k_gemm_mfma<false><<<gemmGrid, 256, 0, stream>>>(act16, W2, dinv, h16, nN);
    k_agg16<<<aggGrid, 256, 0, stream>>>(row_start, row_end, esrc, dinv, h16, b2, act16, nN, nullptr, nullptr);
    k_gemm_mfma<false><<<gemmGrid, 256, 0, stream>>>(act16, W3, dinv, h16, nN);
    k_agg16<<<aggGrid, 256, 0, stream>>>(row_start, row_end, esrc, dinv, h16, b3, nullptr, nN, sums, bat);

    // ---- head ----
    k_mlp<<<G, 64, 0, stream>>>(sums, cnt, lw1, lb1, lw2, lb2, out);
}